// Round 9
// baseline (423.929 us; speedup 1.0000x reference)
//
#include <hip/hip_runtime.h>
#include <stdint.h>

#define DIM 64
#define NE 2048
#define NROWS 65536
#define HW 4096

#define DECAYF 0.99f
#define OMDF ((float)(1.0 - 0.99))
#define EPSF 1e-5f
#define NEPSF ((float)(2048.0 * 1e-5))

typedef const __attribute__((address_space(1))) uint32_t* gas1_t;
typedef __attribute__((address_space(3))) uint32_t* las3_t;

__device__ __forceinline__ void gload16(const float* g, float* l) {
  __builtin_amdgcn_global_load_lds((gas1_t)g, (las3_t)l, 16, 0, 0);
}

// ---------------- se[j] = sum_d E[d][j]^2 ----------------
__global__ __launch_bounds__(256) void se_kernel(const float* __restrict__ E,
                                                 float* __restrict__ se) {
  int j = blockIdx.x * 256 + threadIdx.x;
  float s = 0.f;
#pragma unroll
  for (int d = 0; d < DIM; ++d) {
    float v = E[d * NE + j];
    s += v * v;
  }
  se[j] = s;
}

// ---------------- Et[j][d] = E[d][j]  (for scalar-load streaming) -------
__global__ __launch_bounds__(256) void etranspose_kernel(const float* __restrict__ E,
                                                         float* __restrict__ Et) {
  __shared__ float T[64][65];
  const int tid = threadIdx.x;
  const int j0 = blockIdx.x * 64;
#pragma unroll
  for (int k = 0; k < 16; ++k) {
    int d = k * 4 + (tid >> 6);
    int c = tid & 63;
    T[d][c] = E[d * NE + j0 + c];
  }
  __syncthreads();
#pragma unroll
  for (int k = 0; k < 16; ++k) {
    int cc = k * 4 + (tid >> 6);
    int d = tid & 63;
    Et[(size_t)(j0 + cc) * DIM + d] = T[d][cc];
  }
}

// ---------------- argmin: X stationary in VGPRs, E via scalar pipe ------
// Thread = one row: x[64] held in VGPRs (loaded once). Block = 256 rows x
// one code quarter (blockIdx.y). Code index j is wave-uniform -> Et/se
// loads scalarize to s_load (SGPR operand of v_fma): ZERO LDS traffic,
// no barriers. Rounds 2-8 proved every LDS-tiled fp32 variant pins at
// ~250-290us because the single per-CU LDS pipe (~12cyc/ds_read_b128)
// is ~2x oversubscribed vs the 4 VALU SIMDs; this removes that pipe.
// fmaf d-chain + dist formula identical to r2-r8; cross-quarter merge via
// atomicMin on monotone-encoded (dist,idx) preserves strict-< + lowest-idx.
__global__ __launch_bounds__(256) void argmin_scalar_kernel(
    const float* __restrict__ x, const float* __restrict__ Et,
    const float* __restrict__ se, unsigned long long* __restrict__ packed) {
  const int tid = threadIdx.x;
  const int row = blockIdx.x * 256 + tid;
  const int b = row >> 12;
  const int hw = row & (HW - 1);
  const float* xr = x + (size_t)b * (DIM * HW) + hw;

  float xv[DIM];
#pragma unroll
  for (int d = 0; d < DIM; ++d) xv[d] = xr[d * HW];

  const int j0 = blockIdx.y * (NE / 4);
  float bv = 3.4e38f;
  int bi = j0;
  for (int j = j0; j < j0 + NE / 4; ++j) {
    const float* __restrict__ Ej = Et + (size_t)j * DIM;  // wave-uniform
    float dot = 0.f;
#pragma unroll
    for (int d = 0; d < DIM; ++d) dot = fmaf(xv[d], Ej[d], dot);
    float dist = fmaf(-2.f, dot, se[j]);
    if (dist < bv) { bv = dist; bi = j; }
  }

  unsigned int ub = __float_as_uint(bv);
  unsigned int enc = (ub & 0x80000000u) ? ~ub : (ub | 0x80000000u);
  unsigned long long p = ((unsigned long long)enc << 32) | (unsigned int)bi;
  atomicMin(&packed[row], p);
}

// ---------------- unpack packed (dist,idx) -> ind, ind_f ----------------
__global__ __launch_bounds__(256) void unpack_kernel(const unsigned long long* __restrict__ packed,
                                                     int* __restrict__ ind,
                                                     float* __restrict__ ind_f) {
  const int row = blockIdx.x * 256 + threadIdx.x;
  int idx = (int)(packed[row] & 0xFFFFFFFFull);
  ind[row] = idx;
  ind_f[row] = (float)idx;
}

// ---------------- out (NCHW) + diff ----------------
__global__ __launch_bounds__(256) void outdiff_kernel(const float* __restrict__ x,
                                                      const float* __restrict__ E,
                                                      const int* __restrict__ ind,
                                                      float* __restrict__ out,
                                                      float* __restrict__ diff_acc) {
  const int t = threadIdx.x;
  float local = 0.f;
  const int base = blockIdx.x * 1024;
#pragma unroll
  for (int u = 0; u < 4; ++u) {
    int i = base + u * 256 + t;
    int hw = i & 4095;
    int bc = i >> 12;
    int c = bc & 63;
    int b = bc >> 6;
    int idx = ind[b * 4096 + hw];
    float xv = x[i];
    float qv = E[c * NE + idx];
    float dq = qv - xv;
    out[i] = xv + dq;
    local += dq * dq;
  }
#pragma unroll
  for (int off = 32; off > 0; off >>= 1) local += __shfl_down(local, off, 64);
  __shared__ float wsum[4];
  if ((t & 63) == 0) wsum[t >> 6] = local;
  __syncthreads();
  if (t == 0) {
    float s = wsum[0] + wsum[1] + wsum[2] + wsum[3];
    atomicAdd(diff_acc, s * (1.f / 4194304.f));
  }
}

// ---------------- esum/counts via per-d-plane LDS histograms ------------
__global__ __launch_bounds__(256) void esum_kernel(const float* __restrict__ x,
                                                   const int* __restrict__ ind,
                                                   float* __restrict__ pesum,
                                                   int* __restrict__ pcnt) {
  const int d = blockIdx.x >> 2;
  const int bg = blockIdx.x & 3;
  __shared__ float h[4][NE];   // 32 KB
  __shared__ int cnt[NE];      // 8 KB
  const int tid = threadIdx.x;
  const int w = tid >> 6;
  float* hf = &h[0][0];
#pragma unroll
  for (int u = 0; u < 32; ++u) hf[u * 256 + tid] = 0.f;
  if (d == 0) {
#pragma unroll
    for (int u = 0; u < 8; ++u) cnt[u * 256 + tid] = 0;
  }
  __syncthreads();
  for (int b = bg * 4; b < bg * 4 + 4; ++b) {
    const int* ib = ind + b * 4096;
    const float* xb = x + ((size_t)b * DIM + d) * 4096;
#pragma unroll 4
    for (int it = 0; it < 16; ++it) {
      int i = it * 256 + tid;
      int idx = ib[i];
      float xv = xb[i];
      atomicAdd(&h[w][idx], xv);
      if (d == 0) atomicAdd(&cnt[idx], 1);
    }
  }
  __syncthreads();
  float* pe = pesum + ((size_t)bg * DIM + d) * NE;
#pragma unroll
  for (int u = 0; u < 8; ++u) {
    int j = u * 256 + tid;
    pe[j] = (h[0][j] + h[1][j]) + (h[2][j] + h[3][j]);
  }
  if (d == 0) {
    int* pc = pcnt + bg * NE;
#pragma unroll
    for (int u = 0; u < 8; ++u) {
      int j = u * 256 + tid;
      pc[j] = cnt[j];
    }
  }
}

// ---------------- finalize: new_cluster_size + n (partial counts) -------
__global__ __launch_bounds__(1024) void finalize_a4(const float* __restrict__ cs_in,
                                                    const int* __restrict__ pcnt,
                                                    float* __restrict__ ncs_slot,
                                                    float* __restrict__ n_out) {
  const int t = threadIdx.x;
  float local = 0.f;
#pragma unroll
  for (int u = 0; u < 2; ++u) {
    int k = u * 1024 + t;
    int c = (pcnt[k] + pcnt[NE + k]) + (pcnt[2 * NE + k] + pcnt[3 * NE + k]);
    float v = DECAYF * cs_in[k] + OMDF * (float)c;
    ncs_slot[k] = v;
    local += v;
  }
#pragma unroll
  for (int off = 32; off > 0; off >>= 1) local += __shfl_down(local, off, 64);
  __shared__ float red[16];
  if ((t & 63) == 0) red[t >> 6] = local;
  __syncthreads();
  if (t == 0) {
    float s = 0.f;
#pragma unroll
    for (int k = 0; k < 16; ++k) s += red[k];
    *n_out = s;
  }
}

// ---------------- finalize: new_embed_avg + new_embed (partial esum) ----
__global__ __launch_bounds__(256) void finalize_b4(const float* __restrict__ ea_in,
                                                   const float* __restrict__ pesum,
                                                   const float* __restrict__ ncs_slot,
                                                   const float* __restrict__ n_out,
                                                   float* __restrict__ nea_slot,
                                                   float* __restrict__ ne_slot) {
  const int k = blockIdx.x * 256 + threadIdx.x;  // 131072
  const float n = *n_out;
  const size_t P = (size_t)DIM * NE;
  float es = (pesum[k] + pesum[P + k]) + (pesum[2 * P + k] + pesum[3 * P + k]);
  float nea = DECAYF * ea_in[k] + OMDF * es;
  nea_slot[k] = nea;
  float ncs = ncs_slot[k & (NE - 1)];
  float cs = (ncs + EPSF) / (n + NEPSF) * n;
  ne_slot[k] = nea / cs;
}

// ================= small-workspace fallback path ========================
#define BRF 128
#define TCF 64
#define NTF (NE / TCF)
__global__ __launch_bounds__(256, 1) void argmin_lds_kernel(const float* __restrict__ x,
                                                            const float* __restrict__ E,
                                                            const float* __restrict__ se,
                                                            int* __restrict__ ind,
                                                            float* __restrict__ ind_f) {
  __shared__ float Xs[DIM][BRF];
  __shared__ float Es[DIM][TCF];
  const int tid = threadIdx.x;
  const int rg = tid >> 4;
  const int cg = tid & 15;
  const int B0 = blockIdx.x * BRF;
  const float* xb = x + (size_t)(B0 >> 12) * (DIM * HW) + (B0 & 4095);
#pragma unroll
  for (int k = 0; k < 8; ++k) {
    int flat = k * 1024 + tid * 4;
    gload16(xb + (flat >> 7) * HW + (flat & 127), &Xs[0][0] + flat);
  }
#pragma unroll
  for (int k = 0; k < 4; ++k) {
    int flat = k * 1024 + tid * 4;
    gload16(E + (flat >> 6) * NE + (flat & 63), &Es[0][0] + flat);
  }
  float bv[8];
  int bi[8];
#pragma unroll
  for (int i = 0; i < 8; ++i) { bv[i] = 3.4e38f; bi[i] = 0; }
  for (int t = 0; t < NTF; ++t) {
    __syncthreads();
    float4 pf[4];
    if (t + 1 < NTF) {
#pragma unroll
      for (int k = 0; k < 4; ++k) {
        int flat = k * 1024 + tid * 4;
        pf[k] = *(const float4*)(E + (flat >> 6) * NE + (t + 1) * TCF + (flat & 63));
      }
    }
    float acc[8][4];
#pragma unroll
    for (int i = 0; i < 8; ++i)
#pragma unroll
      for (int j = 0; j < 4; ++j) acc[i][j] = 0.f;
#pragma unroll 4
    for (int d = 0; d < DIM; ++d) {
      float4 x0 = *(const float4*)&Xs[d][rg * 8];
      float4 x1 = *(const float4*)&Xs[d][rg * 8 + 4];
      float4 e0 = *(const float4*)&Es[d][cg * 4];
      float xr[8] = {x0.x, x0.y, x0.z, x0.w, x1.x, x1.y, x1.z, x1.w};
      float er[4] = {e0.x, e0.y, e0.z, e0.w};
#pragma unroll
      for (int i = 0; i < 8; ++i)
#pragma unroll
        for (int j = 0; j < 4; ++j) acc[i][j] = fmaf(xr[i], er[j], acc[i][j]);
    }
    float4 s4 = *(const float4*)(se + t * TCF + cg * 4);
    float sv[4] = {s4.x, s4.y, s4.z, s4.w};
#pragma unroll
    for (int i = 0; i < 8; ++i)
#pragma unroll
      for (int j = 0; j < 4; ++j) {
        float dist = fmaf(-2.f, acc[i][j], sv[j]);
        if (dist < bv[i]) { bv[i] = dist; bi[i] = t * TCF + cg * 4 + j; }
      }
    __syncthreads();
    if (t + 1 < NTF) {
#pragma unroll
      for (int k = 0; k < 4; ++k) {
        int flat = k * 1024 + tid * 4;
        *(float4*)(&Es[0][0] + flat) = pf[k];
      }
    }
  }
#pragma unroll
  for (int i = 0; i < 8; ++i) {
    float v = bv[i];
    int ix = bi[i];
#pragma unroll
    for (int off = 1; off < 16; off <<= 1) {
      float ov = __shfl_xor(v, off, 64);
      int oi = __shfl_xor(ix, off, 64);
      if (ov < v || (ov == v && oi < ix)) { v = ov; ix = oi; }
    }
    bv[i] = v;
    bi[i] = ix;
  }
  if (cg == 0) {
#pragma unroll
    for (int i = 0; i < 8; ++i) {
      int grow = B0 + rg * 8 + i;
      ind[grow] = bi[i];
      ind_f[grow] = (float)bi[i];
    }
  }
}

__global__ __launch_bounds__(256) void scatter_atomic_kernel(const float* __restrict__ x,
                                                             const int* __restrict__ ind,
                                                             float* __restrict__ counts,
                                                             float* __restrict__ esum) {
  const int row = blockIdx.x * 256 + threadIdx.x;
  const int idx = ind[row];
  atomicAdd(&counts[idx], 1.f);
  const int b = row >> 12;
  const int hw = row & 4095;
  const float* xr = x + (size_t)b * (DIM * HW) + hw;
#pragma unroll
  for (int d = 0; d < DIM; ++d) atomicAdd(&esum[d * NE + idx], xr[d * HW]);
}

__global__ __launch_bounds__(1024) void finalize_a_float(const float* __restrict__ cs_in,
                                                         float* __restrict__ ncs_slot,
                                                         float* __restrict__ n_out) {
  const int t = threadIdx.x;
  float local = 0.f;
#pragma unroll
  for (int u = 0; u < 2; ++u) {
    int k = u * 1024 + t;
    float v = DECAYF * cs_in[k] + OMDF * ncs_slot[k];
    ncs_slot[k] = v;
    local += v;
  }
#pragma unroll
  for (int off = 32; off > 0; off >>= 1) local += __shfl_down(local, off, 64);
  __shared__ float red[16];
  if ((t & 63) == 0) red[t >> 6] = local;
  __syncthreads();
  if (t == 0) {
    float s = 0.f;
#pragma unroll
    for (int k = 0; k < 16; ++k) s += red[k];
    *n_out = s;
  }
}

__global__ __launch_bounds__(256) void finalize_b_inplace(const float* __restrict__ ea_in,
                                                          float* __restrict__ nea_slot,
                                                          const float* __restrict__ ncs_slot,
                                                          const float* __restrict__ n_out,
                                                          float* __restrict__ ne_slot) {
  const int k = blockIdx.x * 256 + threadIdx.x;
  const float n = *n_out;
  float nea = DECAYF * ea_in[k] + OMDF * nea_slot[k];
  nea_slot[k] = nea;
  float ncs = ncs_slot[k & (NE - 1)];
  float cs = (ncs + EPSF) / (n + NEPSF) * n;
  ne_slot[k] = nea / cs;
}

extern "C" void kernel_launch(void* const* d_in, const int* in_sizes, int n_in,
                              void* d_out, int out_size, void* d_ws, size_t ws_size,
                              hipStream_t stream) {
  const float* x = (const float*)d_in[0];      // [16,64,64,64]
  const float* E = (const float*)d_in[1];      // [64,2048]
  const float* cs_in = (const float*)d_in[2];  // [2048]
  const float* ea_in = (const float*)d_in[3];  // [64,2048]
  float* out = (float*)d_out;

  const size_t O_OUT = 0;
  const size_t O_DIFF = 4194304;
  const size_t O_IND = 4194305;
  const size_t O_NE = 4259841;    // new_embed [64,2048]
  const size_t O_NCS = 4390913;   // new_cluster_size [2048]
  const size_t O_NEA = 4392961;   // new_embed_avg [64,2048]

  // workspace layout
  float* se = (float*)d_ws;                  // 2048
  int* ind = (int*)(se + NE);                // 65536
  float* n_out = (float*)(ind + NROWS);      // 1 (+3 pad)
  int* pcnt = (int*)(n_out + 4);             // 4*2048
  float* pesum = (float*)(pcnt + 4 * NE);    // 4*131072
  // overlays inside pesum (dead before esum_kernel writes it):
  unsigned long long* packed = (unsigned long long*)pesum;  // 65536 u64 = 131072 f
  float* Et = pesum + 131072;                               // 131072 f
  const size_t need = (size_t)((char*)(pesum + 4 * (size_t)DIM * NE) - (char*)d_ws);
  const bool big_ws = ws_size >= need;

  hipMemsetAsync(out + O_DIFF, 0, 4, stream);
  se_kernel<<<NE / 256, 256, 0, stream>>>(E, se);

  if (big_ws) {
    etranspose_kernel<<<NE / 64, 256, 0, stream>>>(E, Et);
    hipMemsetAsync(packed, 0xFF, (size_t)NROWS * 8, stream);
    dim3 agrid(NROWS / 256, 4, 1);
    argmin_scalar_kernel<<<agrid, 256, 0, stream>>>(x, Et, se, packed);
    unpack_kernel<<<NROWS / 256, 256, 0, stream>>>(packed, ind, out + O_IND);
    outdiff_kernel<<<4096, 256, 0, stream>>>(x, E, ind, out + O_OUT, out + O_DIFF);
    esum_kernel<<<DIM * 4, 256, 0, stream>>>(x, ind, pesum, pcnt);
    finalize_a4<<<1, 1024, 0, stream>>>(cs_in, pcnt, out + O_NCS, n_out);
    finalize_b4<<<DIM * NE / 256, 256, 0, stream>>>(ea_in, pesum, out + O_NCS, n_out,
                                                    out + O_NEA, out + O_NE);
  } else {
    argmin_lds_kernel<<<NROWS / BRF, 256, 0, stream>>>(x, E, se, ind, out + O_IND);
    outdiff_kernel<<<4096, 256, 0, stream>>>(x, E, ind, out + O_OUT, out + O_DIFF);
    hipMemsetAsync(out + O_NCS, 0, NE * 4, stream);
    hipMemsetAsync(out + O_NEA, 0, (size_t)DIM * NE * 4, stream);
    scatter_atomic_kernel<<<NROWS / 256, 256, 0, stream>>>(x, ind, out + O_NCS,
                                                           out + O_NEA);
    finalize_a_float<<<1, 1024, 0, stream>>>(cs_in, out + O_NCS, n_out);
    finalize_b_inplace<<<DIM * NE / 256, 256, 0, stream>>>(ea_in, out + O_NEA,
                                                           out + O_NCS, n_out,
                                                           out + O_NE);
  }
}

// Round 10
// 321.082 us; speedup vs baseline: 1.3203x; 1.3203x over previous
//
#include <hip/hip_runtime.h>
#include <stdint.h>

#define DIM 64
#define NE 2048
#define NROWS 65536
#define HW 4096
#define BR 128          // rows per block
#define TC 128          // codes per tile
#define NT (NE / TC)    // 16 tiles

#define DECAYF 0.99f
#define OMDF ((float)(1.0 - 0.99))
#define EPSF 1e-5f
#define NEPSF ((float)(2048.0 * 1e-5))

// ---------------- se[j] = sum_d E[d][j]^2 ----------------
__global__ __launch_bounds__(256) void se_kernel(const float* __restrict__ E,
                                                 float* __restrict__ se) {
  int j = blockIdx.x * 256 + threadIdx.x;
  float s = 0.f;
#pragma unroll
  for (int d = 0; d < DIM; ++d) {
    float v = E[d * NE + j];
    s += v * v;
  }
  se[j] = s;
}

// ---------------- argmin: round-2 structure + conflict-free E reads -----
// Round 2 (248us, VGPR 88, simple two-sync loop) was the best measured
// argmin; its only proven defect was the cg*8 32B E-read chunks (4-way
// bank conflict, 1.68e7 counts). This is r2 verbatim except the E/se
// reads are split into two 16B chunks at cg*4 / cg*4+64 (r8-proven
// conflict-free) with bi remapped to match -> indices identical.
// All "improvements" tried in r3-r9 (dbuf, gload_lds, reg-prefetch,
// ping-pong, 512thr, scalar-pipe) regressed; keep the simple loop.
__global__ __launch_bounds__(256, 2) void argmin_kernel(const float* __restrict__ x,
                                                        const float* __restrict__ E,
                                                        const float* __restrict__ se,
                                                        int* __restrict__ ind,
                                                        float* __restrict__ ind_f) {
  __shared__ float Xs[DIM][BR];   // [d][row]  32 KB
  __shared__ float Es[DIM][TC];   // [d][code] 32 KB
  const int tid = threadIdx.x;
  const int rg = tid >> 4;   // 0..15
  const int cg = tid & 15;   // 0..15
  const int B0 = blockIdx.x * BR;
  const int b = B0 >> 12;
  const int hw0 = B0 & 4095;
  const float* xb = x + (size_t)b * (DIM * HW) + hw0;

  // ---- stage Xs once: Xs[d][r] = x[b][d][hw0+r] (coalesced float4) ----
  float* Xf = &Xs[0][0];
#pragma unroll
  for (int k = 0; k < 8; ++k) {
    int i = k * 1024 + tid * 4;       // flat over [64][128]
    int d = i >> 7, r = i & 127;
    *(float4*)(Xf + i) = *(const float4*)(xb + d * HW + r);
  }

  float bv[8];
  int bi[8];
#pragma unroll
  for (int i2 = 0; i2 < 8; ++i2) { bv[i2] = 3.4e38f; bi[i2] = 0; }

  float* Ef = &Es[0][0];
  for (int t = 0; t < NT; ++t) {
    __syncthreads();   // prev-tile reads done (and Xs writes ordered on t==0)
#pragma unroll
    for (int k = 0; k < 8; ++k) {
      int i = k * 1024 + tid * 4;     // flat over [64][128]
      int d = i >> 7, c = i & 127;
      *(float4*)(Ef + i) = *(const float4*)(E + d * NE + t * TC + c);
    }
    __syncthreads();

    float acc[8][8];
#pragma unroll
    for (int i2 = 0; i2 < 8; ++i2)
#pragma unroll
      for (int j = 0; j < 8; ++j) acc[i2][j] = 0.f;

#pragma unroll 8
    for (int d = 0; d < DIM; ++d) {   // serial d-chain: same rounding as r1-r9
      float4 xa = *(const float4*)&Xs[d][rg * 8];
      float4 xc = *(const float4*)&Xs[d][rg * 8 + 4];
      float4 ea = *(const float4*)&Es[d][cg * 4];        // 16B chunk (2-way ok)
      float4 ec = *(const float4*)&Es[d][cg * 4 + 64];   // 16B chunk (2-way ok)
      float xr[8] = {xa.x, xa.y, xa.z, xa.w, xc.x, xc.y, xc.z, xc.w};
      float er[8] = {ea.x, ea.y, ea.z, ea.w, ec.x, ec.y, ec.z, ec.w};
#pragma unroll
      for (int i2 = 0; i2 < 8; ++i2)
#pragma unroll
        for (int j = 0; j < 8; ++j) acc[i2][j] = fmaf(xr[i2], er[j], acc[i2][j]);
    }

    // per-tile argmin fold (strict < + ascending visit keeps lowest index)
    float4 s0 = *(const float4*)(se + t * TC + cg * 4);
    float4 s1 = *(const float4*)(se + t * TC + cg * 4 + 64);
    float sv[8] = {s0.x, s0.y, s0.z, s0.w, s1.x, s1.y, s1.z, s1.w};
#pragma unroll
    for (int i2 = 0; i2 < 8; ++i2) {
#pragma unroll
      for (int j = 0; j < 8; ++j) {
        float dist = fmaf(-2.f, acc[i2][j], sv[j]);
        if (dist < bv[i2]) {
          bv[i2] = dist;
          bi[i2] = t * TC + (j >> 2) * 64 + cg * 4 + (j & 3);
        }
      }
    }
  }

  // cross-thread reduce over the 16 cg-lanes of each row group (in-wave)
#pragma unroll
  for (int i2 = 0; i2 < 8; ++i2) {
    float v = bv[i2];
    int ix = bi[i2];
#pragma unroll
    for (int off = 1; off < 16; off <<= 1) {
      float ov = __shfl_xor(v, off, 64);
      int oi = __shfl_xor(ix, off, 64);
      if (ov < v || (ov == v && oi < ix)) { v = ov; ix = oi; }
    }
    bv[i2] = v;
    bi[i2] = ix;
  }
  if (cg == 0) {
#pragma unroll
    for (int i2 = 0; i2 < 8; ++i2) {
      int grow = B0 + rg * 8 + i2;
      ind[grow] = bi[i2];
      ind_f[grow] = (float)bi[i2];
    }
  }
}

// ---------------- out (NCHW) + diff ----------------
__global__ __launch_bounds__(256) void outdiff_kernel(const float* __restrict__ x,
                                                      const float* __restrict__ E,
                                                      const int* __restrict__ ind,
                                                      float* __restrict__ out,
                                                      float* __restrict__ diff_acc) {
  const int t = threadIdx.x;
  float local = 0.f;
  const int base = blockIdx.x * 1024;
#pragma unroll
  for (int u = 0; u < 4; ++u) {
    int i = base + u * 256 + t;
    int hw = i & 4095;
    int bc = i >> 12;
    int c = bc & 63;
    int b = bc >> 6;
    int idx = ind[b * 4096 + hw];
    float xv = x[i];
    float qv = E[c * NE + idx];
    float dq = qv - xv;
    out[i] = xv + dq;
    local += dq * dq;
  }
#pragma unroll
  for (int off = 32; off > 0; off >>= 1) local += __shfl_down(local, off, 64);
  __shared__ float wsum[4];
  if ((t & 63) == 0) wsum[t >> 6] = local;
  __syncthreads();
  if (t == 0) {
    float s = wsum[0] + wsum[1] + wsum[2] + wsum[3];
    atomicAdd(diff_acc, s * (1.f / 4194304.f));
  }
}

// ---------------- esum/counts via per-d-plane LDS histograms ------------
__global__ __launch_bounds__(256) void esum_kernel(const float* __restrict__ x,
                                                   const int* __restrict__ ind,
                                                   float* __restrict__ pesum,
                                                   int* __restrict__ pcnt) {
  const int d = blockIdx.x >> 2;
  const int bg = blockIdx.x & 3;
  __shared__ float h[4][NE];   // 32 KB
  __shared__ int cnt[NE];      // 8 KB
  const int tid = threadIdx.x;
  const int w = tid >> 6;
  float* hf = &h[0][0];
#pragma unroll
  for (int u = 0; u < 32; ++u) hf[u * 256 + tid] = 0.f;
  if (d == 0) {
#pragma unroll
    for (int u = 0; u < 8; ++u) cnt[u * 256 + tid] = 0;
  }
  __syncthreads();
  for (int b = bg * 4; b < bg * 4 + 4; ++b) {
    const int* ib = ind + b * 4096;
    const float* xb = x + ((size_t)b * DIM + d) * 4096;
#pragma unroll 4
    for (int it = 0; it < 16; ++it) {
      int i = it * 256 + tid;
      int idx = ib[i];
      float xv = xb[i];
      atomicAdd(&h[w][idx], xv);
      if (d == 0) atomicAdd(&cnt[idx], 1);
    }
  }
  __syncthreads();
  float* pe = pesum + ((size_t)bg * DIM + d) * NE;
#pragma unroll
  for (int u = 0; u < 8; ++u) {
    int j = u * 256 + tid;
    pe[j] = (h[0][j] + h[1][j]) + (h[2][j] + h[3][j]);
  }
  if (d == 0) {
    int* pc = pcnt + bg * NE;
#pragma unroll
    for (int u = 0; u < 8; ++u) {
      int j = u * 256 + tid;
      pc[j] = cnt[j];
    }
  }
}

// ---------------- finalize: new_cluster_size + n (partial counts) -------
__global__ __launch_bounds__(1024) void finalize_a4(const float* __restrict__ cs_in,
                                                    const int* __restrict__ pcnt,
                                                    float* __restrict__ ncs_slot,
                                                    float* __restrict__ n_out) {
  const int t = threadIdx.x;
  float local = 0.f;
#pragma unroll
  for (int u = 0; u < 2; ++u) {
    int k = u * 1024 + t;
    int c = (pcnt[k] + pcnt[NE + k]) + (pcnt[2 * NE + k] + pcnt[3 * NE + k]);
    float v = DECAYF * cs_in[k] + OMDF * (float)c;
    ncs_slot[k] = v;
    local += v;
  }
#pragma unroll
  for (int off = 32; off > 0; off >>= 1) local += __shfl_down(local, off, 64);
  __shared__ float red[16];
  if ((t & 63) == 0) red[t >> 6] = local;
  __syncthreads();
  if (t == 0) {
    float s = 0.f;
#pragma unroll
    for (int k = 0; k < 16; ++k) s += red[k];
    *n_out = s;
  }
}

// ---------------- finalize: new_embed_avg + new_embed (partial esum) ----
__global__ __launch_bounds__(256) void finalize_b4(const float* __restrict__ ea_in,
                                                   const float* __restrict__ pesum,
                                                   const float* __restrict__ ncs_slot,
                                                   const float* __restrict__ n_out,
                                                   float* __restrict__ nea_slot,
                                                   float* __restrict__ ne_slot) {
  const int k = blockIdx.x * 256 + threadIdx.x;  // 131072
  const float n = *n_out;
  const size_t P = (size_t)DIM * NE;
  float es = (pesum[k] + pesum[P + k]) + (pesum[2 * P + k] + pesum[3 * P + k]);
  float nea = DECAYF * ea_in[k] + OMDF * es;
  nea_slot[k] = nea;
  float ncs = ncs_slot[k & (NE - 1)];
  float cs = (ncs + EPSF) / (n + NEPSF) * n;
  ne_slot[k] = nea / cs;
}

// ---------------- fallback (tiny workspace): atomic scatter -------------
__global__ __launch_bounds__(256) void scatter_atomic_kernel(const float* __restrict__ x,
                                                             const int* __restrict__ ind,
                                                             float* __restrict__ counts,
                                                             float* __restrict__ esum) {
  const int row = blockIdx.x * 256 + threadIdx.x;
  const int idx = ind[row];
  atomicAdd(&counts[idx], 1.f);
  const int b = row >> 12;
  const int hw = row & 4095;
  const float* xr = x + (size_t)b * (DIM * HW) + hw;
#pragma unroll
  for (int d = 0; d < DIM; ++d) atomicAdd(&esum[d * NE + idx], xr[d * HW]);
}

__global__ __launch_bounds__(1024) void finalize_a_float(const float* __restrict__ cs_in,
                                                         float* __restrict__ ncs_slot,
                                                         float* __restrict__ n_out) {
  const int t = threadIdx.x;
  float local = 0.f;
#pragma unroll
  for (int u = 0; u < 2; ++u) {
    int k = u * 1024 + t;
    float v = DECAYF * cs_in[k] + OMDF * ncs_slot[k];
    ncs_slot[k] = v;
    local += v;
  }
#pragma unroll
  for (int off = 32; off > 0; off >>= 1) local += __shfl_down(local, off, 64);
  __shared__ float red[16];
  if ((t & 63) == 0) red[t >> 6] = local;
  __syncthreads();
  if (t == 0) {
    float s = 0.f;
#pragma unroll
    for (int k = 0; k < 16; ++k) s += red[k];
    *n_out = s;
  }
}

__global__ __launch_bounds__(256) void finalize_b_inplace(const float* __restrict__ ea_in,
                                                          float* __restrict__ nea_slot,
                                                          const float* __restrict__ ncs_slot,
                                                          const float* __restrict__ n_out,
                                                          float* __restrict__ ne_slot) {
  const int k = blockIdx.x * 256 + threadIdx.x;
  const float n = *n_out;
  float nea = DECAYF * ea_in[k] + OMDF * nea_slot[k];
  nea_slot[k] = nea;
  float ncs = ncs_slot[k & (NE - 1)];
  float cs = (ncs + EPSF) / (n + NEPSF) * n;
  ne_slot[k] = nea / cs;
}

extern "C" void kernel_launch(void* const* d_in, const int* in_sizes, int n_in,
                              void* d_out, int out_size, void* d_ws, size_t ws_size,
                              hipStream_t stream) {
  const float* x = (const float*)d_in[0];      // [16,64,64,64]
  const float* E = (const float*)d_in[1];      // [64,2048]
  const float* cs_in = (const float*)d_in[2];  // [2048]
  const float* ea_in = (const float*)d_in[3];  // [64,2048]
  float* out = (float*)d_out;

  const size_t O_OUT = 0;
  const size_t O_DIFF = 4194304;
  const size_t O_IND = 4194305;
  const size_t O_NE = 4259841;    // new_embed [64,2048]
  const size_t O_NCS = 4390913;   // new_cluster_size [2048]
  const size_t O_NEA = 4392961;   // new_embed_avg [64,2048]

  // workspace layout
  float* se = (float*)d_ws;                  // 2048
  int* ind = (int*)(se + NE);                // 65536
  float* n_out = (float*)(ind + NROWS);      // 1 (+3 pad)
  int* pcnt = (int*)(n_out + 4);             // 4*2048
  float* pesum = (float*)(pcnt + 4 * NE);    // 4*131072
  const size_t need = (size_t)((char*)(pesum + 4 * (size_t)DIM * NE) - (char*)d_ws);
  const bool big_ws = ws_size >= need;

  hipMemsetAsync(out + O_DIFF, 0, 4, stream);

  se_kernel<<<NE / 256, 256, 0, stream>>>(E, se);
  argmin_kernel<<<NROWS / BR, 256, 0, stream>>>(x, E, se, ind, out + O_IND);
  outdiff_kernel<<<4096, 256, 0, stream>>>(x, E, ind, out + O_OUT, out + O_DIFF);

  if (big_ws) {
    esum_kernel<<<DIM * 4, 256, 0, stream>>>(x, ind, pesum, pcnt);
    finalize_a4<<<1, 1024, 0, stream>>>(cs_in, pcnt, out + O_NCS, n_out);
    finalize_b4<<<DIM * NE / 256, 256, 0, stream>>>(ea_in, pesum, out + O_NCS, n_out,
                                                    out + O_NEA, out + O_NE);
  } else {
    hipMemsetAsync(out + O_NCS, 0, NE * 4, stream);
    hipMemsetAsync(out + O_NEA, 0, (size_t)DIM * NE * 4, stream);
    scatter_atomic_kernel<<<NROWS / 256, 256, 0, stream>>>(x, ind, out + O_NCS,
                                                           out + O_NEA);
    finalize_a_float<<<1, 1024, 0, stream>>>(cs_in, out + O_NCS, n_out);
    finalize_b_inplace<<<DIM * NE / 256, 256, 0, stream>>>(ea_in, out + O_NEA,
                                                           out + O_NCS, n_out,
                                                           out + O_NE);
  }
}

// Round 11
// 176.993 us; speedup vs baseline: 2.3952x; 1.8141x over previous
//
#include <hip/hip_runtime.h>
#include <stdint.h>

#define DIM 64
#define NE 2048
#define NROWS 65536
#define HW 4096

#define DECAYF 0.99f
#define OMDF ((float)(1.0 - 0.99))
#define EPSF 1e-5f
#define NEPSF ((float)(2048.0 * 1e-5))

typedef _Float16 f16x8 __attribute__((ext_vector_type(8)));
typedef float f32x4 __attribute__((ext_vector_type(4)));

#define SPLIT_SCALE 1024.0f
#define SPLIT_INV 0.0009765625f   // 2^-10

// ---------------- se[j] = sum_d E[d][j]^2 ----------------
__global__ __launch_bounds__(256) void se_kernel(const float* __restrict__ E,
                                                 float* __restrict__ se) {
  int j = blockIdx.x * 256 + threadIdx.x;
  float s = 0.f;
#pragma unroll
  for (int d = 0; d < DIM; ++d) {
    float v = E[d * NE + j];
    s += v * v;
  }
  se[j] = s;
}

// ---------------- pack E into MFMA B-fragment order (f16 split) ---------
// B-frag for 16x16x32_f16, tile t (16 codes), kstep ks: lane l holds
// B[k][j] with k = ks*32 + (l>>4)*8 + r (r=0..7), j = t*16 + (l&15).
// Eh = RNE f16 of E; El = f16((E - Eh) * 1024)  [scaled residual].
// Layout: Epk[(t*2+ks)*512 + l*8 + r], one 16B load per lane per frag.
__global__ __launch_bounds__(256) void epack_kernel(const float* __restrict__ E,
                                                    _Float16* __restrict__ Eh,
                                                    _Float16* __restrict__ El) {
  int task = blockIdx.x * 256 + threadIdx.x;  // 16384 = 128 tiles * 2 ks * 64 lanes
  int l = task & 63;
  int ks = (task >> 6) & 1;
  int t = task >> 7;
  int j = t * 16 + (l & 15);
  int d0 = ks * 32 + ((l >> 4) & 3) * 8;
  _Float16 h8[8], l8[8];
#pragma unroll
  for (int r = 0; r < 8; ++r) {
    float v = E[(d0 + r) * NE + j];
    _Float16 h = (_Float16)v;
    h8[r] = h;
    l8[r] = (_Float16)((v - (float)h) * SPLIT_SCALE);
  }
  *(f16x8*)(Eh + (size_t)task * 8) = *(f16x8*)h8;
  *(f16x8*)(El + (size_t)task * 8) = *(f16x8*)l8;
}

// ---------------- argmin via split-f16 MFMA (no LDS, no barriers) -------
// Wave owns 32 rows (2 row-tiles of 16) x all 2048 codes (128 tiles).
// dot = acc1 + acc2*2^-10 where acc1 = sum xh*eh (2 MFMA),
// acc2 = sum xh*el' + xl'*eh (4 MFMA); dropped term xl*el ~ 2e-6 rms,
// same order as the f32-chain-vs-np rounding that passed rounds 1-10.
// dist = fmaf(-2, dot, se[j]); strict < + ascending j + lane tie-break
// on lower index preserves reference argmin semantics.
__global__ __launch_bounds__(256) void argmin_mfma_kernel(
    const float* __restrict__ x, const _Float16* __restrict__ Eh,
    const _Float16* __restrict__ El, const float* __restrict__ se,
    int* __restrict__ ind, float* __restrict__ ind_f) {
  const int tid = threadIdx.x;
  const int lane = tid & 63;
  const int wv = tid >> 6;
  const int R0 = blockIdx.x * 128 + wv * 32;
  const int lg = (lane >> 4) & 3;   // k-group / D-row group
  const int lc = lane & 15;         // A-row / B-col / D-col

  // A-fragments: xh, xl' for 2 row-tiles x 2 ksteps
  f16x8 xh[2][2], xl[2][2];
#pragma unroll
  for (int rt = 0; rt < 2; ++rt) {
#pragma unroll
    for (int ks = 0; ks < 2; ++ks) {
      int r_glob = R0 + rt * 16 + lc;
      const float* xr = x + (size_t)(r_glob >> 12) * (DIM * HW) + (r_glob & 4095);
      int d0 = ks * 32 + lg * 8;
      _Float16 h8[8], l8[8];
#pragma unroll
      for (int e = 0; e < 8; ++e) {
        float v = xr[(d0 + e) * HW];
        _Float16 h = (_Float16)v;
        h8[e] = h;
        l8[e] = (_Float16)((v - (float)h) * SPLIT_SCALE);
      }
      xh[rt][ks] = *(f16x8*)h8;
      xl[rt][ks] = *(f16x8*)l8;
    }
  }

  float bv[2][4];
  int bi[2][4];
#pragma unroll
  for (int rt = 0; rt < 2; ++rt)
#pragma unroll
    for (int q = 0; q < 4; ++q) { bv[rt][q] = 3.4e38f; bi[rt][q] = 0; }

  for (int t = 0; t < NE / 16; ++t) {
    f16x8 bh0 = *(const f16x8*)(Eh + ((size_t)(t * 2 + 0) * 64 + lane) * 8);
    f16x8 bh1 = *(const f16x8*)(Eh + ((size_t)(t * 2 + 1) * 64 + lane) * 8);
    f16x8 bl0 = *(const f16x8*)(El + ((size_t)(t * 2 + 0) * 64 + lane) * 8);
    f16x8 bl1 = *(const f16x8*)(El + ((size_t)(t * 2 + 1) * 64 + lane) * 8);
    float sej = se[t * 16 + lc];

#pragma unroll
    for (int rt = 0; rt < 2; ++rt) {
      f32x4 a1 = {0.f, 0.f, 0.f, 0.f};
      f32x4 a2 = {0.f, 0.f, 0.f, 0.f};
      a1 = __builtin_amdgcn_mfma_f32_16x16x32_f16(xh[rt][0], bh0, a1, 0, 0, 0);
      a1 = __builtin_amdgcn_mfma_f32_16x16x32_f16(xh[rt][1], bh1, a1, 0, 0, 0);
      a2 = __builtin_amdgcn_mfma_f32_16x16x32_f16(xh[rt][0], bl0, a2, 0, 0, 0);
      a2 = __builtin_amdgcn_mfma_f32_16x16x32_f16(xh[rt][1], bl1, a2, 0, 0, 0);
      a2 = __builtin_amdgcn_mfma_f32_16x16x32_f16(xl[rt][0], bh0, a2, 0, 0, 0);
      a2 = __builtin_amdgcn_mfma_f32_16x16x32_f16(xl[rt][1], bh1, a2, 0, 0, 0);
#pragma unroll
      for (int q = 0; q < 4; ++q) {
        float dot = fmaf(a2[q], SPLIT_INV, a1[q]);
        float dist = fmaf(-2.f, dot, sej);
        if (dist < bv[rt][q]) { bv[rt][q] = dist; bi[rt][q] = t * 16 + lc; }
      }
    }
  }

  // reduce over the 16 lanes (lc) holding different column classes
#pragma unroll
  for (int rt = 0; rt < 2; ++rt) {
#pragma unroll
    for (int q = 0; q < 4; ++q) {
      float v = bv[rt][q];
      int ix = bi[rt][q];
#pragma unroll
      for (int off = 1; off < 16; off <<= 1) {
        float ov = __shfl_xor(v, off, 64);
        int oi = __shfl_xor(ix, off, 64);
        if (ov < v || (ov == v && oi < ix)) { v = ov; ix = oi; }
      }
      if (lc == 0) {
        int grow = R0 + rt * 16 + lg * 4 + q;   // D-row = (lane>>4)*4 + q
        ind[grow] = ix;
        ind_f[grow] = (float)ix;
      }
    }
  }
}

// ---------------- out (NCHW) + diff ----------------
__global__ __launch_bounds__(256) void outdiff_kernel(const float* __restrict__ x,
                                                      const float* __restrict__ E,
                                                      const int* __restrict__ ind,
                                                      float* __restrict__ out,
                                                      float* __restrict__ diff_acc) {
  const int t = threadIdx.x;
  float local = 0.f;
  const int base = blockIdx.x * 1024;
#pragma unroll
  for (int u = 0; u < 4; ++u) {
    int i = base + u * 256 + t;
    int hw = i & 4095;
    int bc = i >> 12;
    int c = bc & 63;
    int b = bc >> 6;
    int idx = ind[b * 4096 + hw];
    float xv = x[i];
    float qv = E[c * NE + idx];
    float dq = qv - xv;
    out[i] = xv + dq;
    local += dq * dq;
  }
#pragma unroll
  for (int off = 32; off > 0; off >>= 1) local += __shfl_down(local, off, 64);
  __shared__ float wsum[4];
  if ((t & 63) == 0) wsum[t >> 6] = local;
  __syncthreads();
  if (t == 0) {
    float s = wsum[0] + wsum[1] + wsum[2] + wsum[3];
    atomicAdd(diff_acc, s * (1.f / 4194304.f));
  }
}

// ---------------- esum/counts via per-d-plane LDS histograms ------------
__global__ __launch_bounds__(256) void esum_kernel(const float* __restrict__ x,
                                                   const int* __restrict__ ind,
                                                   float* __restrict__ pesum,
                                                   int* __restrict__ pcnt) {
  const int d = blockIdx.x >> 2;
  const int bg = blockIdx.x & 3;
  __shared__ float h[4][NE];   // 32 KB
  __shared__ int cnt[NE];      // 8 KB
  const int tid = threadIdx.x;
  const int w = tid >> 6;
  float* hf = &h[0][0];
#pragma unroll
  for (int u = 0; u < 32; ++u) hf[u * 256 + tid] = 0.f;
  if (d == 0) {
#pragma unroll
    for (int u = 0; u < 8; ++u) cnt[u * 256 + tid] = 0;
  }
  __syncthreads();
  for (int b = bg * 4; b < bg * 4 + 4; ++b) {
    const int* ib = ind + b * 4096;
    const float* xb = x + ((size_t)b * DIM + d) * 4096;
#pragma unroll 4
    for (int it = 0; it < 16; ++it) {
      int i = it * 256 + tid;
      int idx = ib[i];
      float xv = xb[i];
      atomicAdd(&h[w][idx], xv);
      if (d == 0) atomicAdd(&cnt[idx], 1);
    }
  }
  __syncthreads();
  float* pe = pesum + ((size_t)bg * DIM + d) * NE;
#pragma unroll
  for (int u = 0; u < 8; ++u) {
    int j = u * 256 + tid;
    pe[j] = (h[0][j] + h[1][j]) + (h[2][j] + h[3][j]);
  }
  if (d == 0) {
    int* pc = pcnt + bg * NE;
#pragma unroll
    for (int u = 0; u < 8; ++u) {
      int j = u * 256 + tid;
      pc[j] = cnt[j];
    }
  }
}

// ---------------- finalize: new_cluster_size + n (partial counts) -------
__global__ __launch_bounds__(1024) void finalize_a4(const float* __restrict__ cs_in,
                                                    const int* __restrict__ pcnt,
                                                    float* __restrict__ ncs_slot,
                                                    float* __restrict__ n_out) {
  const int t = threadIdx.x;
  float local = 0.f;
#pragma unroll
  for (int u = 0; u < 2; ++u) {
    int k = u * 1024 + t;
    int c = (pcnt[k] + pcnt[NE + k]) + (pcnt[2 * NE + k] + pcnt[3 * NE + k]);
    float v = DECAYF * cs_in[k] + OMDF * (float)c;
    ncs_slot[k] = v;
    local += v;
  }
#pragma unroll
  for (int off = 32; off > 0; off >>= 1) local += __shfl_down(local, off, 64);
  __shared__ float red[16];
  if ((t & 63) == 0) red[t >> 6] = local;
  __syncthreads();
  if (t == 0) {
    float s = 0.f;
#pragma unroll
    for (int k = 0; k < 16; ++k) s += red[k];
    *n_out = s;
  }
}

// ---------------- finalize: new_embed_avg + new_embed (partial esum) ----
__global__ __launch_bounds__(256) void finalize_b4(const float* __restrict__ ea_in,
                                                   const float* __restrict__ pesum,
                                                   const float* __restrict__ ncs_slot,
                                                   const float* __restrict__ n_out,
                                                   float* __restrict__ nea_slot,
                                                   float* __restrict__ ne_slot) {
  const int k = blockIdx.x * 256 + threadIdx.x;  // 131072
  const float n = *n_out;
  const size_t P = (size_t)DIM * NE;
  float es = (pesum[k] + pesum[P + k]) + (pesum[2 * P + k] + pesum[3 * P + k]);
  float nea = DECAYF * ea_in[k] + OMDF * es;
  nea_slot[k] = nea;
  float ncs = ncs_slot[k & (NE - 1)];
  float cs = (ncs + EPSF) / (n + NEPSF) * n;
  ne_slot[k] = nea / cs;
}

// ================= small-workspace fallback path (r10, proven) ==========
#define BRF 128
#define TCF 128
#define NTF (NE / TCF)
__global__ __launch_bounds__(256, 2) void argmin_lds_kernel(const float* __restrict__ x,
                                                            const float* __restrict__ E,
                                                            const float* __restrict__ se,
                                                            int* __restrict__ ind,
                                                            float* __restrict__ ind_f) {
  __shared__ float Xs[DIM][BRF];
  __shared__ float Es[DIM][TCF];
  const int tid = threadIdx.x;
  const int rg = tid >> 4;
  const int cg = tid & 15;
  const int B0 = blockIdx.x * BRF;
  const float* xb = x + (size_t)(B0 >> 12) * (DIM * HW) + (B0 & 4095);
  float* Xf = &Xs[0][0];
#pragma unroll
  for (int k = 0; k < 8; ++k) {
    int i = k * 1024 + tid * 4;
    *(float4*)(Xf + i) = *(const float4*)(xb + (i >> 7) * HW + (i & 127));
  }
  float bv[8];
  int bi[8];
#pragma unroll
  for (int i2 = 0; i2 < 8; ++i2) { bv[i2] = 3.4e38f; bi[i2] = 0; }
  float* Ef = &Es[0][0];
  for (int t = 0; t < NTF; ++t) {
    __syncthreads();
#pragma unroll
    for (int k = 0; k < 8; ++k) {
      int i = k * 1024 + tid * 4;
      *(float4*)(Ef + i) = *(const float4*)(E + (i >> 7) * NE + t * TCF + (i & 127));
    }
    __syncthreads();
    float acc[8][8];
#pragma unroll
    for (int i2 = 0; i2 < 8; ++i2)
#pragma unroll
      for (int j = 0; j < 8; ++j) acc[i2][j] = 0.f;
#pragma unroll 8
    for (int d = 0; d < DIM; ++d) {
      float4 xa = *(const float4*)&Xs[d][rg * 8];
      float4 xc = *(const float4*)&Xs[d][rg * 8 + 4];
      float4 ea = *(const float4*)&Es[d][cg * 4];
      float4 ec = *(const float4*)&Es[d][cg * 4 + 64];
      float xr[8] = {xa.x, xa.y, xa.z, xa.w, xc.x, xc.y, xc.z, xc.w};
      float er[8] = {ea.x, ea.y, ea.z, ea.w, ec.x, ec.y, ec.z, ec.w};
#pragma unroll
      for (int i2 = 0; i2 < 8; ++i2)
#pragma unroll
        for (int j = 0; j < 8; ++j) acc[i2][j] = fmaf(xr[i2], er[j], acc[i2][j]);
    }
    float4 s0 = *(const float4*)(se + t * TCF + cg * 4);
    float4 s1 = *(const float4*)(se + t * TCF + cg * 4 + 64);
    float sv[8] = {s0.x, s0.y, s0.z, s0.w, s1.x, s1.y, s1.z, s1.w};
#pragma unroll
    for (int i2 = 0; i2 < 8; ++i2) {
#pragma unroll
      for (int j = 0; j < 8; ++j) {
        float dist = fmaf(-2.f, acc[i2][j], sv[j]);
        if (dist < bv[i2]) {
          bv[i2] = dist;
          bi[i2] = t * TCF + (j >> 2) * 64 + cg * 4 + (j & 3);
        }
      }
    }
  }
#pragma unroll
  for (int i2 = 0; i2 < 8; ++i2) {
    float v = bv[i2];
    int ix = bi[i2];
#pragma unroll
    for (int off = 1; off < 16; off <<= 1) {
      float ov = __shfl_xor(v, off, 64);
      int oi = __shfl_xor(ix, off, 64);
      if (ov < v || (ov == v && oi < ix)) { v = ov; ix = oi; }
    }
    bv[i2] = v;
    bi[i2] = ix;
  }
  if (cg == 0) {
#pragma unroll
    for (int i2 = 0; i2 < 8; ++i2) {
      int grow = B0 + rg * 8 + i2;
      ind[grow] = bi[i2];
      ind_f[grow] = (float)bi[i2];
    }
  }
}

__global__ __launch_bounds__(256) void scatter_atomic_kernel(const float* __restrict__ x,
                                                             const int* __restrict__ ind,
                                                             float* __restrict__ counts,
                                                             float* __restrict__ esum) {
  const int row = blockIdx.x * 256 + threadIdx.x;
  const int idx = ind[row];
  atomicAdd(&counts[idx], 1.f);
  const int b = row >> 12;
  const int hw = row & 4095;
  const float* xr = x + (size_t)b * (DIM * HW) + hw;
#pragma unroll
  for (int d = 0; d < DIM; ++d) atomicAdd(&esum[d * NE + idx], xr[d * HW]);
}

__global__ __launch_bounds__(1024) void finalize_a_float(const float* __restrict__ cs_in,
                                                         float* __restrict__ ncs_slot,
                                                         float* __restrict__ n_out) {
  const int t = threadIdx.x;
  float local = 0.f;
#pragma unroll
  for (int u = 0; u < 2; ++u) {
    int k = u * 1024 + t;
    float v = DECAYF * cs_in[k] + OMDF * ncs_slot[k];
    ncs_slot[k] = v;
    local += v;
  }
#pragma unroll
  for (int off = 32; off > 0; off >>= 1) local += __shfl_down(local, off, 64);
  __shared__ float red[16];
  if ((t & 63) == 0) red[t >> 6] = local;
  __syncthreads();
  if (t == 0) {
    float s = 0.f;
#pragma unroll
    for (int k = 0; k < 16; ++k) s += red[k];
    *n_out = s;
  }
}

__global__ __launch_bounds__(256) void finalize_b_inplace(const float* __restrict__ ea_in,
                                                          float* __restrict__ nea_slot,
                                                          const float* __restrict__ ncs_slot,
                                                          const float* __restrict__ n_out,
                                                          float* __restrict__ ne_slot) {
  const int k = blockIdx.x * 256 + threadIdx.x;
  const float n = *n_out;
  float nea = DECAYF * ea_in[k] + OMDF * nea_slot[k];
  nea_slot[k] = nea;
  float ncs = ncs_slot[k & (NE - 1)];
  float cs = (ncs + EPSF) / (n + NEPSF) * n;
  ne_slot[k] = nea / cs;
}

extern "C" void kernel_launch(void* const* d_in, const int* in_sizes, int n_in,
                              void* d_out, int out_size, void* d_ws, size_t ws_size,
                              hipStream_t stream) {
  const float* x = (const float*)d_in[0];      // [16,64,64,64]
  const float* E = (const float*)d_in[1];      // [64,2048]
  const float* cs_in = (const float*)d_in[2];  // [2048]
  const float* ea_in = (const float*)d_in[3];  // [64,2048]
  float* out = (float*)d_out;

  const size_t O_OUT = 0;
  const size_t O_DIFF = 4194304;
  const size_t O_IND = 4194305;
  const size_t O_NE = 4259841;    // new_embed [64,2048]
  const size_t O_NCS = 4390913;   // new_cluster_size [2048]
  const size_t O_NEA = 4392961;   // new_embed_avg [64,2048]

  // workspace layout
  float* se = (float*)d_ws;                  // 2048
  int* ind = (int*)(se + NE);                // 65536
  float* n_out = (float*)(ind + NROWS);      // 1 (+3 pad)
  int* pcnt = (int*)(n_out + 4);             // 4*2048
  float* pesum = (float*)(pcnt + 4 * NE);    // 4*131072
  // Epk overlays pesum (dead until esum_kernel writes it, after argmin)
  _Float16* Ehpk = (_Float16*)pesum;         // 131072 f16 = 256 KB
  _Float16* Elpk = Ehpk + (size_t)DIM * NE;  // 131072 f16
  const size_t need = (size_t)((char*)(pesum + 4 * (size_t)DIM * NE) - (char*)d_ws);
  const bool big_ws = ws_size >= need;

  hipMemsetAsync(out + O_DIFF, 0, 4, stream);
  se_kernel<<<NE / 256, 256, 0, stream>>>(E, se);

  if (big_ws) {
    epack_kernel<<<64, 256, 0, stream>>>(E, Ehpk, Elpk);
    argmin_mfma_kernel<<<NROWS / 128, 256, 0, stream>>>(x, Ehpk, Elpk, se, ind,
                                                        out + O_IND);
    outdiff_kernel<<<4096, 256, 0, stream>>>(x, E, ind, out + O_OUT, out + O_DIFF);
    esum_kernel<<<DIM * 4, 256, 0, stream>>>(x, ind, pesum, pcnt);
    finalize_a4<<<1, 1024, 0, stream>>>(cs_in, pcnt, out + O_NCS, n_out);
    finalize_b4<<<DIM * NE / 256, 256, 0, stream>>>(ea_in, pesum, out + O_NCS, n_out,
                                                    out + O_NEA, out + O_NE);
  } else {
    argmin_lds_kernel<<<NROWS / BRF, 256, 0, stream>>>(x, E, se, ind, out + O_IND);
    outdiff_kernel<<<4096, 256, 0, stream>>>(x, E, ind, out + O_OUT, out + O_DIFF);
    hipMemsetAsync(out + O_NCS, 0, NE * 4, stream);
    hipMemsetAsync(out + O_NEA, 0, (size_t)DIM * NE * 4, stream);
    scatter_atomic_kernel<<<NROWS / 256, 256, 0, stream>>>(x, ind, out + O_NCS,
                                                           out + O_NEA);
    finalize_a_float<<<1, 1024, 0, stream>>>(cs_in, out + O_NCS, n_out);
    finalize_b_inplace<<<DIM * NE / 256, 256, 0, stream>>>(ea_in, out + O_NEA,
                                                           out + O_NCS, n_out,
                                                           out + O_NE);
  }
}

// Round 12
// 111.346 us; speedup vs baseline: 3.8073x; 1.5896x over previous
//
#include <hip/hip_runtime.h>
#include <stdint.h>

#define DIM 64
#define NE 2048
#define NROWS 65536
#define HW 4096

#define DECAYF 0.99f
#define OMDF ((float)(1.0 - 0.99))
#define EPSF 1e-5f
#define NEPSF ((float)(2048.0 * 1e-5))

typedef _Float16 f16x8 __attribute__((ext_vector_type(8)));
typedef float f32x4 __attribute__((ext_vector_type(4)));

#define SPLIT_SCALE 1024.0f
#define SPLIT_INV 0.0009765625f   // 2^-10

// ---------------- se[j] = sum_d E[d][j]^2 ----------------
__global__ __launch_bounds__(256) void se_kernel(const float* __restrict__ E,
                                                 float* __restrict__ se) {
  int j = blockIdx.x * 256 + threadIdx.x;
  float s = 0.f;
#pragma unroll
  for (int d = 0; d < DIM; ++d) {
    float v = E[d * NE + j];
    s += v * v;
  }
  se[j] = s;
}

// ---------------- pack E into MFMA B-fragment order (f16 split) ---------
__global__ __launch_bounds__(256) void epack_kernel(const float* __restrict__ E,
                                                    _Float16* __restrict__ Eh,
                                                    _Float16* __restrict__ El) {
  int task = blockIdx.x * 256 + threadIdx.x;  // 16384 = 128 tiles * 2 ks * 64 lanes
  int l = task & 63;
  int ks = (task >> 6) & 1;
  int t = task >> 7;
  int j = t * 16 + (l & 15);
  int d0 = ks * 32 + ((l >> 4) & 3) * 8;
  _Float16 h8[8], l8[8];
#pragma unroll
  for (int r = 0; r < 8; ++r) {
    float v = E[(d0 + r) * NE + j];
    _Float16 h = (_Float16)v;
    h8[r] = h;
    l8[r] = (_Float16)((v - (float)h) * SPLIT_SCALE);
  }
  *(f16x8*)(Eh + (size_t)task * 8) = *(f16x8*)h8;
  *(f16x8*)(El + (size_t)task * 8) = *(f16x8*)l8;
}

// ---------------- argmin via split-f16 MFMA + ping-pong B prefetch ------
// r11 structure (91us, MfmaUtil 23%) was L2-latency-bound: B-frags loaded
// at loop top, consumed immediately -> ~300cy stall per tile. Ping-pong
// register double-buffer (only +32 VGPR on a 60-VGPR kernel) hides the
// load latency under tile t's 12 MFMAs + fold. MFMA order identical to
// r11 -> bit-identical indices.
#define MFMA16(A, B, C) __builtin_amdgcn_mfma_f32_16x16x32_f16(A, B, C, 0, 0, 0)

#define COMPUTE_TILE(T, B0, B1, B2, B3, SEJ)                              \
  {                                                                       \
    _Pragma("unroll") for (int rt = 0; rt < 2; ++rt) {                    \
      f32x4 a1 = {0.f, 0.f, 0.f, 0.f};                                    \
      f32x4 a2 = {0.f, 0.f, 0.f, 0.f};                                    \
      a1 = MFMA16(xh[rt][0], B0, a1);                                     \
      a1 = MFMA16(xh[rt][1], B1, a1);                                     \
      a2 = MFMA16(xh[rt][0], B2, a2);                                     \
      a2 = MFMA16(xh[rt][1], B3, a2);                                     \
      a2 = MFMA16(xl[rt][0], B0, a2);                                     \
      a2 = MFMA16(xl[rt][1], B1, a2);                                     \
      _Pragma("unroll") for (int q = 0; q < 4; ++q) {                     \
        float dot = fmaf(a2[q], SPLIT_INV, a1[q]);                        \
        float dist = fmaf(-2.f, dot, SEJ);                                \
        if (dist < bv[rt][q]) { bv[rt][q] = dist; bi[rt][q] = (T)*16 + lc; } \
      }                                                                   \
    }                                                                     \
  }

__global__ __launch_bounds__(256) void argmin_mfma_kernel(
    const float* __restrict__ x, const _Float16* __restrict__ Eh,
    const _Float16* __restrict__ El, const float* __restrict__ se,
    int* __restrict__ ind, float* __restrict__ ind_f) {
  const int tid = threadIdx.x;
  const int lane = tid & 63;
  const int wv = tid >> 6;
  const int R0 = blockIdx.x * 128 + wv * 32;
  const int lg = (lane >> 4) & 3;   // k-group / D-row group
  const int lc = lane & 15;         // A-row / B-col / D-col

  // A-fragments: xh, xl' for 2 row-tiles x 2 ksteps
  f16x8 xh[2][2], xl[2][2];
#pragma unroll
  for (int rt = 0; rt < 2; ++rt) {
#pragma unroll
    for (int ks = 0; ks < 2; ++ks) {
      int r_glob = R0 + rt * 16 + lc;
      const float* xr = x + (size_t)(r_glob >> 12) * (DIM * HW) + (r_glob & 4095);
      int d0 = ks * 32 + lg * 8;
      _Float16 h8[8], l8[8];
#pragma unroll
      for (int e = 0; e < 8; ++e) {
        float v = xr[(d0 + e) * HW];
        _Float16 h = (_Float16)v;
        h8[e] = h;
        l8[e] = (_Float16)((v - (float)h) * SPLIT_SCALE);
      }
      xh[rt][ks] = *(f16x8*)h8;
      xl[rt][ks] = *(f16x8*)l8;
    }
  }

  float bv[2][4];
  int bi[2][4];
#pragma unroll
  for (int rt = 0; rt < 2; ++rt)
#pragma unroll
    for (int q = 0; q < 4; ++q) { bv[rt][q] = 3.4e38f; bi[rt][q] = 0; }

  const size_t lo = (size_t)lane * 8;
  // current buffer <- tile 0
  f16x8 c0 = *(const f16x8*)(Eh + lo);
  f16x8 c1 = *(const f16x8*)(Eh + 512 + lo);
  f16x8 c2 = *(const f16x8*)(El + lo);
  f16x8 c3 = *(const f16x8*)(El + 512 + lo);
  float seC = se[lc];

  for (int t = 0; t < NE / 16; t += 2) {
    // prefetch tile t+1 (always exists: 128 tiles, t even)
    f16x8 n0 = *(const f16x8*)(Eh + (size_t)(t + 1) * 1024 + lo);
    f16x8 n1 = *(const f16x8*)(Eh + (size_t)(t + 1) * 1024 + 512 + lo);
    f16x8 n2 = *(const f16x8*)(El + (size_t)(t + 1) * 1024 + lo);
    f16x8 n3 = *(const f16x8*)(El + (size_t)(t + 1) * 1024 + 512 + lo);
    float seN = se[(t + 1) * 16 + lc];

    COMPUTE_TILE(t, c0, c1, c2, c3, seC);

    if (t + 2 < NE / 16) {   // prefetch tile t+2
      c0 = *(const f16x8*)(Eh + (size_t)(t + 2) * 1024 + lo);
      c1 = *(const f16x8*)(Eh + (size_t)(t + 2) * 1024 + 512 + lo);
      c2 = *(const f16x8*)(El + (size_t)(t + 2) * 1024 + lo);
      c3 = *(const f16x8*)(El + (size_t)(t + 2) * 1024 + 512 + lo);
      seC = se[(t + 2) * 16 + lc];
    }

    COMPUTE_TILE(t + 1, n0, n1, n2, n3, seN);
  }

  // reduce over the 16 lanes (lc) holding different column classes
#pragma unroll
  for (int rt = 0; rt < 2; ++rt) {
#pragma unroll
    for (int q = 0; q < 4; ++q) {
      float v = bv[rt][q];
      int ix = bi[rt][q];
#pragma unroll
      for (int off = 1; off < 16; off <<= 1) {
        float ov = __shfl_xor(v, off, 64);
        int oi = __shfl_xor(ix, off, 64);
        if (ov < v || (ov == v && oi < ix)) { v = ov; ix = oi; }
      }
      if (lc == 0) {
        int grow = R0 + rt * 16 + lg * 4 + q;   // D-row = (lane>>4)*4 + q
        ind[grow] = ix;
        ind_f[grow] = (float)ix;
      }
    }
  }
}

// ---- fused: out (NCHW) + diff + esum/counts per-d-plane histograms -----
// Block (d, bg) streams x plane [b][d][:] once: writes out = xv + (qv-xv),
// accumulates diff, and histograms xv into h[wave][idx]. Replaces the
// separate outdiff kernel (which re-read all of x).
__global__ __launch_bounds__(256) void esum_fused_kernel(const float* __restrict__ x,
                                                         const float* __restrict__ E,
                                                         const int* __restrict__ ind,
                                                         float* __restrict__ out,
                                                         float* __restrict__ diff_acc,
                                                         float* __restrict__ pesum,
                                                         int* __restrict__ pcnt) {
  const int d = blockIdx.x >> 2;
  const int bg = blockIdx.x & 3;
  __shared__ float h[4][NE];   // 32 KB
  __shared__ int cnt[NE];      // 8 KB
  const int tid = threadIdx.x;
  const int w = tid >> 6;
  float* hf = &h[0][0];
#pragma unroll
  for (int u = 0; u < 32; ++u) hf[u * 256 + tid] = 0.f;
  if (d == 0) {
#pragma unroll
    for (int u = 0; u < 8; ++u) cnt[u * 256 + tid] = 0;
  }
  __syncthreads();
  const float* Ed = E + d * NE;
  float local = 0.f;
  for (int b = bg * 4; b < bg * 4 + 4; ++b) {
    const int* ib = ind + b * 4096;
    const float* xb = x + ((size_t)b * DIM + d) * 4096;
    float* ob = out + ((size_t)b * DIM + d) * 4096;
#pragma unroll 4
    for (int it = 0; it < 16; ++it) {
      int i = it * 256 + tid;
      int idx = ib[i];
      float xv = xb[i];
      float qv = Ed[idx];
      float dq = qv - xv;
      ob[i] = xv + dq;          // replicate xp + (quantize - xp)
      local += dq * dq;
      atomicAdd(&h[w][idx], xv);
      if (d == 0) atomicAdd(&cnt[idx], 1);
    }
  }
  // diff partial: wave reduce -> block reduce -> one atomic
#pragma unroll
  for (int off = 32; off > 0; off >>= 1) local += __shfl_down(local, off, 64);
  __shared__ float wsum[4];
  if ((tid & 63) == 0) wsum[tid >> 6] = local;
  __syncthreads();
  if (tid == 0) {
    float s = (wsum[0] + wsum[1]) + (wsum[2] + wsum[3]);
    atomicAdd(diff_acc, s * (1.f / 4194304.f));
  }
  float* pe = pesum + ((size_t)bg * DIM + d) * NE;
#pragma unroll
  for (int u = 0; u < 8; ++u) {
    int j = u * 256 + tid;
    pe[j] = (h[0][j] + h[1][j]) + (h[2][j] + h[3][j]);
  }
  if (d == 0) {
    int* pc = pcnt + bg * NE;
#pragma unroll
    for (int u = 0; u < 8; ++u) {
      int j = u * 256 + tid;
      pc[j] = cnt[j];
    }
  }
}

// ---------------- finalize: new_cluster_size + n (partial counts) -------
__global__ __launch_bounds__(1024) void finalize_a4(const float* __restrict__ cs_in,
                                                    const int* __restrict__ pcnt,
                                                    float* __restrict__ ncs_slot,
                                                    float* __restrict__ n_out) {
  const int t = threadIdx.x;
  float local = 0.f;
#pragma unroll
  for (int u = 0; u < 2; ++u) {
    int k = u * 1024 + t;
    int c = (pcnt[k] + pcnt[NE + k]) + (pcnt[2 * NE + k] + pcnt[3 * NE + k]);
    float v = DECAYF * cs_in[k] + OMDF * (float)c;
    ncs_slot[k] = v;
    local += v;
  }
#pragma unroll
  for (int off = 32; off > 0; off >>= 1) local += __shfl_down(local, off, 64);
  __shared__ float red[16];
  if ((t & 63) == 0) red[t >> 6] = local;
  __syncthreads();
  if (t == 0) {
    float s = 0.f;
#pragma unroll
    for (int k = 0; k < 16; ++k) s += red[k];
    *n_out = s;
  }
}

// ---------------- finalize: new_embed_avg + new_embed (partial esum) ----
__global__ __launch_bounds__(256) void finalize_b4(const float* __restrict__ ea_in,
                                                   const float* __restrict__ pesum,
                                                   const float* __restrict__ ncs_slot,
                                                   const float* __restrict__ n_out,
                                                   float* __restrict__ nea_slot,
                                                   float* __restrict__ ne_slot) {
  const int k = blockIdx.x * 256 + threadIdx.x;  // 131072
  const float n = *n_out;
  const size_t P = (size_t)DIM * NE;
  float es = (pesum[k] + pesum[P + k]) + (pesum[2 * P + k] + pesum[3 * P + k]);
  float nea = DECAYF * ea_in[k] + OMDF * es;
  nea_slot[k] = nea;
  float ncs = ncs_slot[k & (NE - 1)];
  float cs = (ncs + EPSF) / (n + NEPSF) * n;
  ne_slot[k] = nea / cs;
}

// ================= small-workspace fallback path (r10, proven) ==========
#define BRF 128
#define TCF 128
#define NTF (NE / TCF)
__global__ __launch_bounds__(256, 2) void argmin_lds_kernel(const float* __restrict__ x,
                                                            const float* __restrict__ E,
                                                            const float* __restrict__ se,
                                                            int* __restrict__ ind,
                                                            float* __restrict__ ind_f) {
  __shared__ float Xs[DIM][BRF];
  __shared__ float Es[DIM][TCF];
  const int tid = threadIdx.x;
  const int rg = tid >> 4;
  const int cg = tid & 15;
  const int B0 = blockIdx.x * BRF;
  const float* xb = x + (size_t)(B0 >> 12) * (DIM * HW) + (B0 & 4095);
  float* Xf = &Xs[0][0];
#pragma unroll
  for (int k = 0; k < 8; ++k) {
    int i = k * 1024 + tid * 4;
    *(float4*)(Xf + i) = *(const float4*)(xb + (i >> 7) * HW + (i & 127));
  }
  float bv[8];
  int bi[8];
#pragma unroll
  for (int i2 = 0; i2 < 8; ++i2) { bv[i2] = 3.4e38f; bi[i2] = 0; }
  float* Ef = &Es[0][0];
  for (int t = 0; t < NTF; ++t) {
    __syncthreads();
#pragma unroll
    for (int k = 0; k < 8; ++k) {
      int i = k * 1024 + tid * 4;
      *(float4*)(Ef + i) = *(const float4*)(E + (i >> 7) * NE + t * TCF + (i & 127));
    }
    __syncthreads();
    float acc[8][8];
#pragma unroll
    for (int i2 = 0; i2 < 8; ++i2)
#pragma unroll
      for (int j = 0; j < 8; ++j) acc[i2][j] = 0.f;
#pragma unroll 8
    for (int d = 0; d < DIM; ++d) {
      float4 xa = *(const float4*)&Xs[d][rg * 8];
      float4 xc = *(const float4*)&Xs[d][rg * 8 + 4];
      float4 ea = *(const float4*)&Es[d][cg * 4];
      float4 ec = *(const float4*)&Es[d][cg * 4 + 64];
      float xr[8] = {xa.x, xa.y, xa.z, xa.w, xc.x, xc.y, xc.z, xc.w};
      float er[8] = {ea.x, ea.y, ea.z, ea.w, ec.x, ec.y, ec.z, ec.w};
#pragma unroll
      for (int i2 = 0; i2 < 8; ++i2)
#pragma unroll
        for (int j = 0; j < 8; ++j) acc[i2][j] = fmaf(xr[i2], er[j], acc[i2][j]);
    }
    float4 s0 = *(const float4*)(se + t * TCF + cg * 4);
    float4 s1 = *(const float4*)(se + t * TCF + cg * 4 + 64);
    float sv[8] = {s0.x, s0.y, s0.z, s0.w, s1.x, s1.y, s1.z, s1.w};
#pragma unroll
    for (int i2 = 0; i2 < 8; ++i2) {
#pragma unroll
      for (int j = 0; j < 8; ++j) {
        float dist = fmaf(-2.f, acc[i2][j], sv[j]);
        if (dist < bv[i2]) {
          bv[i2] = dist;
          bi[i2] = t * TCF + (j >> 2) * 64 + cg * 4 + (j & 3);
        }
      }
    }
  }
#pragma unroll
  for (int i2 = 0; i2 < 8; ++i2) {
    float v = bv[i2];
    int ix = bi[i2];
#pragma unroll
    for (int off = 1; off < 16; off <<= 1) {
      float ov = __shfl_xor(v, off, 64);
      int oi = __shfl_xor(ix, off, 64);
      if (ov < v || (ov == v && oi < ix)) { v = ov; ix = oi; }
    }
    bv[i2] = v;
    bi[i2] = ix;
  }
  if (cg == 0) {
#pragma unroll
    for (int i2 = 0; i2 < 8; ++i2) {
      int grow = B0 + rg * 8 + i2;
      ind[grow] = bi[i2];
      ind_f[grow] = (float)bi[i2];
    }
  }
}

__global__ __launch_bounds__(256) void outdiff_kernel(const float* __restrict__ x,
                                                      const float* __restrict__ E,
                                                      const int* __restrict__ ind,
                                                      float* __restrict__ out,
                                                      float* __restrict__ diff_acc) {
  const int t = threadIdx.x;
  float local = 0.f;
  const int base = blockIdx.x * 1024;
#pragma unroll
  for (int u = 0; u < 4; ++u) {
    int i = base + u * 256 + t;
    int hw = i & 4095;
    int bc = i >> 12;
    int c = bc & 63;
    int b = bc >> 6;
    int idx = ind[b * 4096 + hw];
    float xv = x[i];
    float qv = E[c * NE + idx];
    float dq = qv - xv;
    out[i] = xv + dq;
    local += dq * dq;
  }
#pragma unroll
  for (int off = 32; off > 0; off >>= 1) local += __shfl_down(local, off, 64);
  __shared__ float wsum[4];
  if ((t & 63) == 0) wsum[t >> 6] = local;
  __syncthreads();
  if (t == 0) {
    float s = wsum[0] + wsum[1] + wsum[2] + wsum[3];
    atomicAdd(diff_acc, s * (1.f / 4194304.f));
  }
}

__global__ __launch_bounds__(256) void scatter_atomic_kernel(const float* __restrict__ x,
                                                             const int* __restrict__ ind,
                                                             float* __restrict__ counts,
                                                             float* __restrict__ esum) {
  const int row = blockIdx.x * 256 + threadIdx.x;
  const int idx = ind[row];
  atomicAdd(&counts[idx], 1.f);
  const int b = row >> 12;
  const int hw = row & 4095;
  const float* xr = x + (size_t)b * (DIM * HW) + hw;
#pragma unroll
  for (int d = 0; d < DIM; ++d) atomicAdd(&esum[d * NE + idx], xr[d * HW]);
}

__global__ __launch_bounds__(1024) void finalize_a_float(const float* __restrict__ cs_in,
                                                         float* __restrict__ ncs_slot,
                                                         float* __restrict__ n_out) {
  const int t = threadIdx.x;
  float local = 0.f;
#pragma unroll
  for (int u = 0; u < 2; ++u) {
    int k = u * 1024 + t;
    float v = DECAYF * cs_in[k] + OMDF * ncs_slot[k];
    ncs_slot[k] = v;
    local += v;
  }
#pragma unroll
  for (int off = 32; off > 0; off >>= 1) local += __shfl_down(local, off, 64);
  __shared__ float red[16];
  if ((t & 63) == 0) red[t >> 6] = local;
  __syncthreads();
  if (t == 0) {
    float s = 0.f;
#pragma unroll
    for (int k = 0; k < 16; ++k) s += red[k];
    *n_out = s;
  }
}

__global__ __launch_bounds__(256) void finalize_b_inplace(const float* __restrict__ ea_in,
                                                          float* __restrict__ nea_slot,
                                                          const float* __restrict__ ncs_slot,
                                                          const float* __restrict__ n_out,
                                                          float* __restrict__ ne_slot) {
  const int k = blockIdx.x * 256 + threadIdx.x;
  const float n = *n_out;
  float nea = DECAYF * ea_in[k] + OMDF * nea_slot[k];
  nea_slot[k] = nea;
  float ncs = ncs_slot[k & (NE - 1)];
  float cs = (ncs + EPSF) / (n + NEPSF) * n;
  ne_slot[k] = nea / cs;
}

extern "C" void kernel_launch(void* const* d_in, const int* in_sizes, int n_in,
                              void* d_out, int out_size, void* d_ws, size_t ws_size,
                              hipStream_t stream) {
  const float* x = (const float*)d_in[0];      // [16,64,64,64]
  const float* E = (const float*)d_in[1];      // [64,2048]
  const float* cs_in = (const float*)d_in[2];  // [2048]
  const float* ea_in = (const float*)d_in[3];  // [64,2048]
  float* out = (float*)d_out;

  const size_t O_OUT = 0;
  const size_t O_DIFF = 4194304;
  const size_t O_IND = 4194305;
  const size_t O_NE = 4259841;    // new_embed [64,2048]
  const size_t O_NCS = 4390913;   // new_cluster_size [2048]
  const size_t O_NEA = 4392961;   // new_embed_avg [64,2048]

  // workspace layout
  float* se = (float*)d_ws;                  // 2048
  int* ind = (int*)(se + NE);                // 65536
  float* n_out = (float*)(ind + NROWS);      // 1 (+3 pad)
  int* pcnt = (int*)(n_out + 4);             // 4*2048
  float* pesum = (float*)(pcnt + 4 * NE);    // 4*131072
  // Epk overlays pesum (dead until esum_fused writes it, after argmin)
  _Float16* Ehpk = (_Float16*)pesum;         // 131072 f16 = 256 KB
  _Float16* Elpk = Ehpk + (size_t)DIM * NE;  // 131072 f16
  const size_t need = (size_t)((char*)(pesum + 4 * (size_t)DIM * NE) - (char*)d_ws);
  const bool big_ws = ws_size >= need;

  hipMemsetAsync(out + O_DIFF, 0, 4, stream);
  se_kernel<<<NE / 256, 256, 0, stream>>>(E, se);

  if (big_ws) {
    epack_kernel<<<64, 256, 0, stream>>>(E, Ehpk, Elpk);
    argmin_mfma_kernel<<<NROWS / 128, 256, 0, stream>>>(x, Ehpk, Elpk, se, ind,
                                                        out + O_IND);
    esum_fused_kernel<<<DIM * 4, 256, 0, stream>>>(x, E, ind, out + O_OUT,
                                                   out + O_DIFF, pesum, pcnt);
    finalize_a4<<<1, 1024, 0, stream>>>(cs_in, pcnt, out + O_NCS, n_out);
    finalize_b4<<<DIM * NE / 256, 256, 0, stream>>>(ea_in, pesum, out + O_NCS, n_out,
                                                    out + O_NEA, out + O_NE);
  } else {
    argmin_lds_kernel<<<NROWS / BRF, 256, 0, stream>>>(x, E, se, ind, out + O_IND);
    outdiff_kernel<<<4096, 256, 0, stream>>>(x, E, ind, out + O_OUT, out + O_DIFF);
    hipMemsetAsync(out + O_NCS, 0, NE * 4, stream);
    hipMemsetAsync(out + O_NEA, 0, (size_t)DIM * NE * 4, stream);
    scatter_atomic_kernel<<<NROWS / 256, 256, 0, stream>>>(x, ind, out + O_NCS,
                                                           out + O_NEA);
    finalize_a_float<<<1, 1024, 0, stream>>>(cs_in, out + O_NCS, n_out);
    finalize_b_inplace<<<DIM * NE / 256, 256, 0, stream>>>(ea_in, out + O_NEA,
                                                           out + O_NCS, n_out,
                                                           out + O_NE);
  }
}